// Round 6
// baseline (561.819 us; speedup 1.0000x reference)
//
#include <hip/hip_runtime.h>
#include <hip/hip_bf16.h>

// EdgeConv fused GNN. R10: msg occupancy 2->3 waves/SIMD.
// - msg: 768 threads / 12 waves, dual-group 32 edges/tile (R8/R9-verified math).
//   LDS holds W1 + W3 + bias + 12x8KB act = 160,000 B exactly.
//   W2 (32 KB) streamed from global (L2/L1-resident, 32 reads/tile, overlapped).
// - memset(agg) folded into wconv (one fewer dispatch): 3 dispatches total.
// - Aggregation by fp32 atomicAdd at end of msg (R9-verified).
// - upd unchanged (R7-R9 verified).

typedef __attribute__((ext_vector_type(8))) short s16x8;   // MFMA A/B frag (8 bf16)
typedef __attribute__((ext_vector_type(4))) float f32x4;   // MFMA C/D frag

__device__ __forceinline__ unsigned short f2bf(float x) {
  union { float f; unsigned u; } v; v.f = x;
  unsigned r = v.u + 0x7fffu + ((v.u >> 16) & 1u);   // RNE
  return (unsigned short)(r >> 16);
}

__device__ __forceinline__ s16x8 ld_cvt8(const float* p) {
  float4 a = *(const float4*)p;
  float4 b = *(const float4*)(p + 4);
  union { s16x8 v; __hip_bfloat162 h2[4]; } u;
  float2 t;
  t.x = a.x; t.y = a.y; u.h2[0] = __float22bfloat162_rn(t);
  t.x = a.z; t.y = a.w; u.h2[1] = __float22bfloat162_rn(t);
  t.x = b.x; t.y = b.y; u.h2[2] = __float22bfloat162_rn(t);
  t.x = b.z; t.y = b.w; u.h2[3] = __float22bfloat162_rn(t);
  return u.v;
}

// ---------------- weight transpose+convert + agg zeroing ----------------
// ushort offsets in wts (global):
//  mW1t @0     : 128 rows x stride 168 (k<160, unswizzled; pad never read)
//  mW2t @21504 : 128 x 128, XOR-swizzled
//  mW3t @37888 :  64 x 128, XOR-swizzled
//  uW1t @46080 : 128 x 128, uW2t @62464, uW3t @78848 (64x128); total 87040 ushorts
__global__ __launch_bounds__(256) void wconv(
    const float* __restrict__ mW1, const float* __restrict__ mW2, const float* __restrict__ mW3,
    const float* __restrict__ uW1, const float* __restrict__ uW2, const float* __restrict__ uW3,
    unsigned short* __restrict__ wts, float* __restrict__ agg, int aggv4) {
  int t = blockIdx.x * 256 + threadIdx.x;
  if (t >= 86016) {
    int i = t - 86016;
    if (i < aggv4) ((float4*)agg)[i] = (float4){0.f, 0.f, 0.f, 0.f};
    return;
  }
  const float* src; int K, N, off, base;
  if      (t < 20480) { src = mW1; K = 160; N = 128; off = 0;     base = 0;     }
  else if (t < 36864) { src = mW2; K = 128; N = 128; off = 20480; base = 21504; }
  else if (t < 45056) { src = mW3; K = 128; N = 64;  off = 36864; base = 37888; }
  else if (t < 61440) { src = uW1; K = 128; N = 128; off = 45056; base = 46080; }
  else if (t < 77824) { src = uW2; K = 128; N = 128; off = 61440; base = 62464; }
  else                { src = uW3; K = 128; N = 64;  off = 77824; base = 78848; }
  int local = t - off;
  int n = local / K, k = local - n * K;
  int idx;
  if (K == 160) idx = n * 168 + k;                                        // mW1t: padded, plain
  else          idx = base + n * 128 + ((((k >> 3) ^ (n & 7)) << 3) | (k & 7));
  wts[idx] = f2bf(src[k * N + n]);
}

// bias LDS layout (floats, from bias base):
//  b1 @0   : [l15*12 + nt] nt<8  (stride 12 for b128 alignment + bank spread)
//  b2 @192 : same
//  b3 @384, g @448, bt @512 : [l15*4 + nt] nt<4
__device__ __forceinline__ void stage_bias(float* bf, int tid, int nthr,
    const float* b1, const float* b2, const float* b3,
    const float* g, const float* bt) {
  for (int i = tid; i < 576; i += nthr) {
    float v = 0.f;
    if (i < 192)      { int c = i;       int l = c / 12, nt = c % 12; if (nt < 8) v = b1[nt * 16 + l]; }
    else if (i < 384) { int c = i - 192; int l = c / 12, nt = c % 12; if (nt < 8) v = b2[nt * 16 + l]; }
    else if (i < 448) { int c = i - 384; int l = c / 4,  nt = c % 4;  v = b3[nt * 16 + l]; }
    else if (i < 512) { int c = i - 448; int l = c / 4,  nt = c % 4;  v = g[nt * 16 + l]; }
    else              { int c = i - 512; int l = c / 4,  nt = c % 4;  v = bt[nt * 16 + l]; }
    bf[i] = v;
  }
}

// ---------------- message MLP: 12 waves, 32 edges/tile/wave, dual-group + atomic agg ----------------
// LDS (ushort offsets): W1 @0 (21504), W3 @21504 (8192), bias @29696 (1152), act @30848 (12*4096)
__global__ __attribute__((amdgpu_flat_work_group_size(768, 768), amdgpu_waves_per_eu(3, 4)))
void msg_kernel(
    const float* __restrict__ h, const int* __restrict__ ei, const float* __restrict__ ea,
    const unsigned short* __restrict__ wts,
    const float* __restrict__ mb1, const float* __restrict__ mb2, const float* __restrict__ mb3,
    const float* __restrict__ mg, const float* __restrict__ mbt,
    float* __restrict__ msg_out, float* __restrict__ agg, int E) {
  __shared__ __align__(16) unsigned short lds[80000];   // 160,000 B
  const int tid = threadIdx.x;
  const int w = tid >> 6, lane = tid & 63, quad = lane >> 4, l15 = lane & 15;
  const int sw = l15 & 7;
  const int* srcI = ei;
  const int* dstI = ei + E;
  const int ntiles = (E + 31) >> 5;
  const int stride = gridDim.x * 12;
  int tile = blockIdx.x * 12 + w;

  // stage W1 (2688 chunks) + W3 (1024 chunks) + biases
  for (int i = tid; i < 3712; i += 768) {
    if (i < 2688) *(s16x8*)&lds[i * 8] = *(const s16x8*)&wts[i * 8];
    else          *(s16x8*)&lds[21504 + (i - 2688) * 8] = *(const s16x8*)&wts[37888 + (i - 2688) * 8];
  }
  float* bf = (float*)&lds[29696];
  stage_bias(bf, tid, 768, mb1, mb2, mb3, mg, mbt);
  __syncthreads();

  unsigned short* act = &lds[30848 + w * 4096];   // per-wave 8KB: 32 rows x 128, swizzled
  const unsigned short* W1 = &lds[0];
  const unsigned short* W3 = &lds[21504];
  const unsigned short* W2g = wts + 21504;        // streamed from L2/L1

  for (; tile < ntiles; tile += stride) {
    const int e0 = tile << 5;
    // ---- gather both 16-edge groups' A-fragments
    int ep1 = e0 + l15, ep2 = e0 + 16 + l15;
    int ec1 = ep1 < E ? ep1 : E - 1;
    int ec2 = ep2 < E ? ep2 : E - 1;
    int s1 = srcI[ec1], d1 = dstI[ec1];
    int s2 = srcI[ec2], d2 = dstI[ec2];
    const float* rs1 = h + (size_t)s1 * 64 + quad * 8;
    const float* rd1 = h + (size_t)d1 * 64 + quad * 8;
    const float* re1 = ea + (size_t)ec1 * 32 + quad * 8;
    const float* rs2 = h + (size_t)s2 * 64 + quad * 8;
    const float* rd2 = h + (size_t)d2 * 64 + quad * 8;
    const float* re2 = ea + (size_t)ec2 * 32 + quad * 8;
    s16x8 fa1[5], fa2[5];
    fa1[0] = ld_cvt8(rs1); fa1[1] = ld_cvt8(rs1 + 32);
    fa1[2] = ld_cvt8(rd1); fa1[3] = ld_cvt8(rd1 + 32);
    fa1[4] = ld_cvt8(re1);
    fa2[0] = ld_cvt8(rs2); fa2[1] = ld_cvt8(rs2 + 32);
    fa2[2] = ld_cvt8(rd2); fa2[3] = ld_cvt8(rd2 + 32);
    fa2[4] = ld_cvt8(re2);

    // ---- L1: 160 -> 128; each W1 fragment feeds both groups
    f32x4 aA[8], aB[8];
    #pragma unroll
    for (int nt = 0; nt < 8; nt++) { aA[nt] = (f32x4){0.f,0.f,0.f,0.f}; aB[nt] = (f32x4){0.f,0.f,0.f,0.f}; }
    #pragma unroll
    for (int kb = 0; kb < 5; kb++) {
      #pragma unroll
      for (int nt = 0; nt < 8; nt++) {
        s16x8 b = *(const s16x8*)&W1[(nt * 16 + l15) * 168 + kb * 32 + quad * 8];
        aA[nt] = __builtin_amdgcn_mfma_f32_16x16x32_bf16(fa1[kb], b, aA[nt], 0, 0, 0);
        aB[nt] = __builtin_amdgcn_mfma_f32_16x16x32_bf16(fa2[kb], b, aB[nt], 0, 0, 0);
      }
    }
    // act1 = relu(acc + b1); rows 0-15 = group1, 16-31 = group2
    {
      union { float4 v[2]; float f[8]; } b1u;
      b1u.v[0] = *(const float4*)&bf[l15 * 12];
      b1u.v[1] = *(const float4*)&bf[l15 * 12 + 4];
      #pragma unroll
      for (int g = 0; g < 2; g++) {
        #pragma unroll
        for (int nt = 0; nt < 8; nt++) {
          int cb = 2 * nt + (l15 >> 3);
          #pragma unroll
          for (int r = 0; r < 4; r++) {
            int row = g * 16 + quad * 4 + r;
            int cbx = cb ^ (row & 7) ^ ((row >> 3) << 2);
            float v = (g ? aB[nt][r] : aA[nt][r]) + b1u.f[nt];
            v = v > 0.f ? v : 0.f;
            act[row * 128 + (cbx << 3) + sw] = f2bf(v);
          }
        }
      }
    }

    // ---- L2: 128 -> 128; A-frags from LDS act, B (W2) streamed from global
    f32x4 cA[8], cB[8];
    #pragma unroll
    for (int nt = 0; nt < 8; nt++) { cA[nt] = (f32x4){0.f,0.f,0.f,0.f}; cB[nt] = (f32x4){0.f,0.f,0.f,0.f}; }
    const int hi1 = (l15 >> 3) << 2;        // (row>>3)<<2 for row=l15
    const int hi2 = (2 + (l15 >> 3)) << 2;  // for row=16+l15
    #pragma unroll
    for (int kb = 0; kb < 4; kb++) {
      int base = (kb << 2) + quad;
      s16x8 a1 = *(const s16x8*)&act[l15 * 128 + (((base ^ sw ^ hi1)) << 3)];
      s16x8 a2 = *(const s16x8*)&act[(16 + l15) * 128 + (((base ^ sw ^ hi2)) << 3)];
      int wblk = (base ^ sw) << 3;
      #pragma unroll
      for (int nt = 0; nt < 8; nt++) {
        s16x8 b = *(const s16x8*)&W2g[(nt * 16 + l15) * 128 + wblk];
        cA[nt] = __builtin_amdgcn_mfma_f32_16x16x32_bf16(a1, b, cA[nt], 0, 0, 0);
        cB[nt] = __builtin_amdgcn_mfma_f32_16x16x32_bf16(a2, b, cB[nt], 0, 0, 0);
      }
    }
    {
      union { float4 v[2]; float f[8]; } b2u;
      b2u.v[0] = *(const float4*)&bf[192 + l15 * 12];
      b2u.v[1] = *(const float4*)&bf[192 + l15 * 12 + 4];
      #pragma unroll
      for (int g = 0; g < 2; g++) {
        #pragma unroll
        for (int nt = 0; nt < 8; nt++) {
          int cb = 2 * nt + (l15 >> 3);
          #pragma unroll
          for (int r = 0; r < 4; r++) {
            int row = g * 16 + quad * 4 + r;
            int cbx = cb ^ (row & 7) ^ ((row >> 3) << 2);
            float v = (g ? cB[nt][r] : cA[nt][r]) + b2u.f[nt];
            v = v > 0.f ? v : 0.f;
            act[row * 128 + (cbx << 3) + sw] = f2bf(v);
          }
        }
      }
    }

    // ---- L3: 128 -> 64 (W3 from LDS)
    f32x4 dA[4], dB[4];
    #pragma unroll
    for (int nt = 0; nt < 4; nt++) { dA[nt] = (f32x4){0.f,0.f,0.f,0.f}; dB[nt] = (f32x4){0.f,0.f,0.f,0.f}; }
    #pragma unroll
    for (int kb = 0; kb < 4; kb++) {
      int base = (kb << 2) + quad;
      s16x8 a1 = *(const s16x8*)&act[l15 * 128 + (((base ^ sw ^ hi1)) << 3)];
      s16x8 a2 = *(const s16x8*)&act[(16 + l15) * 128 + (((base ^ sw ^ hi2)) << 3)];
      int wblk = (base ^ sw) << 3;
      #pragma unroll
      for (int nt = 0; nt < 4; nt++) {
        s16x8 b = *(const s16x8*)&W3[(nt * 16 + l15) * 128 + wblk];
        dA[nt] = __builtin_amdgcn_mfma_f32_16x16x32_bf16(a1, b, dA[nt], 0, 0, 0);
        dB[nt] = __builtin_amdgcn_mfma_f32_16x16x32_bf16(a2, b, dB[nt], 0, 0, 0);
      }
    }

    // ---- LayerNorm in registers + store msg + atomic aggregate into agg[dst]
    {
      union { float4 v; float f[4]; } b3u, gu, btu;
      b3u.v = *(const float4*)&bf[384 + l15 * 4];
      gu.v  = *(const float4*)&bf[448 + l15 * 4];
      btu.v = *(const float4*)&bf[512 + l15 * 4];
      #pragma unroll
      for (int g = 0; g < 2; g++) {
        #pragma unroll
        for (int r = 0; r < 4; r++) {
          float v0 = (g ? dB[0][r] : dA[0][r]) + b3u.f[0];
          float v1 = (g ? dB[1][r] : dA[1][r]) + b3u.f[1];
          float v2 = (g ? dB[2][r] : dA[2][r]) + b3u.f[2];
          float v3 = (g ? dB[3][r] : dA[3][r]) + b3u.f[3];
          float p = v0 + v1 + v2 + v3;
          float q = v0 * v0 + v1 * v1 + v2 * v2 + v3 * v3;
          #pragma unroll
          for (int m = 1; m <= 8; m <<= 1) {
            p += __shfl_xor(p, m);
            q += __shfl_xor(q, m);
          }
          float mu = p * (1.f / 64.f);
          float var = q * (1.f / 64.f) - mu * mu;
          float rstd = rsqrtf(var + 1e-5f);
          int row = e0 + g * 16 + quad * 4 + r;
          if (row < E) {
            float o0 = (v0 - mu) * rstd * gu.f[0] + btu.f[0];
            float o1 = (v1 - mu) * rstd * gu.f[1] + btu.f[1];
            float o2 = (v2 - mu) * rstd * gu.f[2] + btu.f[2];
            float o3 = (v3 - mu) * rstd * gu.f[3] + btu.f[3];
            float* mp = msg_out + (size_t)row * 64 + l15;
            mp[0]  = o0;
            mp[16] = o1;
            mp[32] = o2;
            mp[48] = o3;
            // dst of this row's edge lives in lane (quad*4+r) of the same group
            int dd = __shfl(g ? d2 : d1, quad * 4 + r);
            float* ap = agg + (size_t)dd * 64 + l15;
            atomicAdd(ap,      o0);
            atomicAdd(ap + 16, o1);
            atomicAdd(ap + 32, o2);
            atomicAdd(ap + 48, o3);
          }
        }
      }
    }
  }
}

// ---------------- update MLP: 16 waves, 16 nodes/tile/wave (R7-R9 verified) ----------------
__global__ __attribute__((amdgpu_flat_work_group_size(1024, 1024), amdgpu_waves_per_eu(4, 4)))
void upd_kernel(
    const float* __restrict__ h, const float* __restrict__ agg,
    const unsigned short* __restrict__ wts,
    const float* __restrict__ ub1, const float* __restrict__ ub2, const float* __restrict__ ub3,
    const float* __restrict__ ug, const float* __restrict__ ubt,
    float* __restrict__ h_new, int Nn) {
  __shared__ __align__(16) unsigned short lds[74880];   // 149,760 B
  const int tid = threadIdx.x;
  const int w = tid >> 6, lane = tid & 63, quad = lane >> 4, l15 = lane & 15;
  const int sw = l15 & 7;
  const int ntiles = (Nn + 15) >> 4;
  const int stride = gridDim.x * 16;
  int tile = blockIdx.x * 16 + w;

  float4 P[8];
  if (tile < ntiles) {
    int n = (tile << 4) + l15; int nc = n < Nn ? n : 0;
    const float* rh = h + (size_t)nc * 64 + quad * 8;
    const float* rg = agg + (size_t)nc * 64 + quad * 8;
    P[0] = *(const float4*)rh;        P[1] = *(const float4*)(rh + 4);
    P[2] = *(const float4*)(rh + 32); P[3] = *(const float4*)(rh + 36);
    P[4] = *(const float4*)rg;        P[5] = *(const float4*)(rg + 4);
    P[6] = *(const float4*)(rg + 32); P[7] = *(const float4*)(rg + 36);
  }

  for (int i = tid; i < 5120; i += 1024)
    *(s16x8*)&lds[i * 8] = *(const s16x8*)&wts[46080 + i * 8];
  float* bf = (float*)&lds[73728];
  stage_bias(bf, tid, 1024, ub1, ub2, ub3, ug, ubt);
  __syncthreads();

  unsigned short* act = &lds[40960 + w * 2048];
  const unsigned short* W1 = &lds[0];
  const unsigned short* W2 = &lds[16384];
  const unsigned short* W3 = &lds[32768];

  for (; tile < ntiles; tile += stride) {
    const int n0 = tile << 4;
    s16x8 fa[4];
    {
      union { s16x8 v; __hip_bfloat162 h2[4]; } u0, u1, u2, u3;
      float2 t;
      t.x = P[0].x; t.y = P[0].y; u0.h2[0] = __float22bfloat162_rn(t);
      t.x = P[0].z; t.y = P[0].w; u0.h2[1] = __float22bfloat162_rn(t);
      t.x = P[1].x; t.y = P[1].y; u0.h2[2] = __float22bfloat162_rn(t);
      t.x = P[1].z; t.y = P[1].w; u0.h2[3] = __float22bfloat162_rn(t);
      t.x = P[2].x; t.y = P[2].y; u1.h2[0] = __float22bfloat162_rn(t);
      t.x = P[2].z; t.y = P[2].w; u1.h2[1] = __float22bfloat162_rn(t);
      t.x = P[3].x; t.y = P[3].y; u1.h2[2] = __float22bfloat162_rn(t);
      t.x = P[3].z; t.y = P[3].w; u1.h2[3] = __float22bfloat162_rn(t);
      t.x = P[4].x; t.y = P[4].y; u2.h2[0] = __float22bfloat162_rn(t);
      t.x = P[4].z; t.y = P[4].w; u2.h2[1] = __float22bfloat162_rn(t);
      t.x = P[5].x; t.y = P[5].y; u2.h2[2] = __float22bfloat162_rn(t);
      t.x = P[5].z; t.y = P[5].w; u2.h2[3] = __float22bfloat162_rn(t);
      t.x = P[6].x; t.y = P[6].y; u3.h2[0] = __float22bfloat162_rn(t);
      t.x = P[6].z; t.y = P[6].w; u3.h2[1] = __float22bfloat162_rn(t);
      t.x = P[7].x; t.y = P[7].y; u3.h2[2] = __float22bfloat162_rn(t);
      t.x = P[7].z; t.y = P[7].w; u3.h2[3] = __float22bfloat162_rn(t);
      fa[0] = u0.v; fa[1] = u1.v; fa[2] = u2.v; fa[3] = u3.v;
    }

    {
      int tn = tile + stride;
      if (tn < ntiles) {
        int n = (tn << 4) + l15; int nc = n < Nn ? n : 0;
        const float* rh = h + (size_t)nc * 64 + quad * 8;
        const float* rg = agg + (size_t)nc * 64 + quad * 8;
        P[0] = *(const float4*)rh;        P[1] = *(const float4*)(rh + 4);
        P[2] = *(const float4*)(rh + 32); P[3] = *(const float4*)(rh + 36);
        P[4] = *(const float4*)rg;        P[5] = *(const float4*)(rg + 4);
        P[6] = *(const float4*)(rg + 32); P[7] = *(const float4*)(rg + 36);
      }
    }

    f32x4 acc[8];
    #pragma unroll
    for (int nt = 0; nt < 8; nt++) acc[nt] = (f32x4){0.f, 0.f, 0.f, 0.f};
    #pragma unroll
    for (int kb = 0; kb < 4; kb++) {
      int blk8 = (((kb << 2) + quad) ^ sw) << 3;
      #pragma unroll
      for (int nt = 0; nt < 8; nt++) {
        s16x8 b = *(const s16x8*)&W1[(nt * 16 + l15) * 128 + blk8];
        acc[nt] = __builtin_amdgcn_mfma_f32_16x16x32_bf16(fa[kb], b, acc[nt], 0, 0, 0);
      }
    }
    {
      union { float4 v[2]; float f[8]; } b1u;
      b1u.v[0] = *(const float4*)&bf[l15 * 12];
      b1u.v[1] = *(const float4*)&bf[l15 * 12 + 4];
      #pragma unroll
      for (int nt = 0; nt < 8; nt++) {
        int cb = 2 * nt + (l15 >> 3);
        #pragma unroll
        for (int r = 0; r < 4; r++) {
          int row = quad * 4 + r;
          float v = acc[nt][r] + b1u.f[nt];
          v = v > 0.f ? v : 0.f;
          act[row * 128 + ((cb ^ (row & 7)) << 3) + sw] = f2bf(v);
        }
      }
    }

    f32x4 acc2[8];
    #pragma unroll
    for (int nt = 0; nt < 8; nt++) acc2[nt] = (f32x4){0.f, 0.f, 0.f, 0.f};
    #pragma unroll
    for (int kb = 0; kb < 4; kb++) {
      int blk8 = (((kb << 2) + quad) ^ sw) << 3;
      s16x8 a = *(const s16x8*)&act[l15 * 128 + blk8];
      #pragma unroll
      for (int nt = 0; nt < 8; nt++) {
        s16x8 b = *(const s16x8*)&W2[(nt * 16 + l15) * 128 + blk8];
        acc2[nt] = __builtin_amdgcn_mfma_f32_16x16x32_bf16(a, b, acc2[nt], 0, 0, 0);
      }
    }
    {
      union { float4 v[2]; float f[8]; } b2u;
      b2u.v[0] = *(const float4*)&bf[192 + l15 * 12];
      b2u.v[1] = *(const float4*)&bf[192 + l15 * 12 + 4];
      #pragma unroll
      for (int nt = 0; nt < 8; nt++) {
        int cb = 2 * nt + (l15 >> 3);
        #pragma unroll
        for (int r = 0; r < 4; r++) {
          int row = quad * 4 + r;
          float v = acc2[nt][r] + b2u.f[nt];
          v = v > 0.f ? v : 0.f;
          act[row * 128 + ((cb ^ (row & 7)) << 3) + sw] = f2bf(v);
        }
      }
    }

    f32x4 acc3[4];
    #pragma unroll
    for (int nt = 0; nt < 4; nt++) acc3[nt] = (f32x4){0.f, 0.f, 0.f, 0.f};
    #pragma unroll
    for (int kb = 0; kb < 4; kb++) {
      int blk8 = (((kb << 2) + quad) ^ sw) << 3;
      s16x8 a = *(const s16x8*)&act[l15 * 128 + blk8];
      #pragma unroll
      for (int nt = 0; nt < 4; nt++) {
        s16x8 b = *(const s16x8*)&W3[(nt * 16 + l15) * 128 + blk8];
        acc3[nt] = __builtin_amdgcn_mfma_f32_16x16x32_bf16(a, b, acc3[nt], 0, 0, 0);
      }
    }

    {
      union { float4 v; float f[4]; } b3u, gu, btu;
      b3u.v = *(const float4*)&bf[384 + l15 * 4];
      gu.v  = *(const float4*)&bf[448 + l15 * 4];
      btu.v = *(const float4*)&bf[512 + l15 * 4];
      #pragma unroll
      for (int r = 0; r < 4; r++) {
        float v0 = acc3[0][r] + b3u.f[0];
        float v1 = acc3[1][r] + b3u.f[1];
        float v2 = acc3[2][r] + b3u.f[2];
        float v3 = acc3[3][r] + b3u.f[3];
        float p = v0 + v1 + v2 + v3;
        float q = v0 * v0 + v1 * v1 + v2 * v2 + v3 * v3;
        #pragma unroll
        for (int m = 1; m <= 8; m <<= 1) {
          p += __shfl_xor(p, m);
          q += __shfl_xor(q, m);
        }
        float mu = p * (1.f / 64.f);
        float var = q * (1.f / 64.f) - mu * mu;
        float rstd = rsqrtf(var + 1e-5f);
        int row = n0 + quad * 4 + r;
        if (row < Nn) {
          const float* hp = h + (size_t)row * 64 + l15;
          float* op = h_new + (size_t)row * 64 + l15;
          op[0]  = (v0 - mu) * rstd * gu.f[0] + btu.f[0] + hp[0];
          op[16] = (v1 - mu) * rstd * gu.f[1] + btu.f[1] + hp[16];
          op[32] = (v2 - mu) * rstd * gu.f[2] + btu.f[2] + hp[32];
          op[48] = (v3 - mu) * rstd * gu.f[3] + btu.f[3] + hp[48];
        }
      }
    }
  }
}

extern "C" void kernel_launch(void* const* d_in, const int* in_sizes, int n_in,
                              void* d_out, int out_size, void* d_ws, size_t ws_size,
                              hipStream_t stream) {
  const float* h   = (const float*)d_in[0];
  const int*   ei  = (const int*)d_in[1];
  const float* ea  = (const float*)d_in[2];
  const float* mW1 = (const float*)d_in[3];
  const float* mb1 = (const float*)d_in[4];
  const float* mW2 = (const float*)d_in[5];
  const float* mb2 = (const float*)d_in[6];
  const float* mW3 = (const float*)d_in[7];
  const float* mb3 = (const float*)d_in[8];
  const float* mg  = (const float*)d_in[9];
  const float* mbt = (const float*)d_in[10];
  const float* uW1 = (const float*)d_in[11];
  const float* ub1 = (const float*)d_in[12];
  const float* uW2 = (const float*)d_in[13];
  const float* ub2 = (const float*)d_in[14];
  const float* uW3 = (const float*)d_in[15];
  const float* ub3 = (const float*)d_in[16];
  const float* ug  = (const float*)d_in[17];
  const float* ubt = (const float*)d_in[18];

  const int N = in_sizes[0] / 64;
  const int E = in_sizes[2] / 32;

  char* ws = (char*)d_ws;
  float* agg          = (float*)ws;              ws += (size_t)N * 64 * 4;
  unsigned short* wts = (unsigned short*)ws;     ws += 87040 * 2;

  float* h_new = (float*)d_out;
  float* msg   = (float*)d_out + (size_t)N * 64;

  const int aggv4 = N * 16;                       // N*64 floats / 4
  const int wz_threads = 86016 + aggv4;
  wconv<<<dim3((wz_threads + 255) / 256), dim3(256), 0, stream>>>(
      mW1, mW2, mW3, uW1, uW2, uW3, wts, agg, aggv4);
  msg_kernel<<<dim3(256), dim3(768), 0, stream>>>(
      h, ei, ea, wts, mb1, mb2, mb3, mg, mbt, msg, agg, E);
  upd_kernel<<<dim3(256), dim3(1024), 0, stream>>>(
      h, agg, wts, ub1, ub2, ub3, ug, ubt, h_new, N);
}

// Round 7
// 321.876 us; speedup vs baseline: 1.7455x; 1.7455x over previous
//
#include <hip/hip_runtime.h>
#include <hip/hip_bf16.h>

// EdgeConv fused GNN. R11: full revert of msg to R9-verified structure
// (R10's occupancy gamble lost ~2x to spill + HBM W2 traffic), plus:
// - index-only prefetch in msg (next tile's src/dst indices loaded one
//   iteration ahead; +4 VGPRs, removes index-load latency from tile head).
// - fused wconv + agg-zero kept (3 dispatches total).
// - msg: 512 thr / 8 waves, 32 edges/tile, dual-group MFMA, all weights in LDS,
//   waves_per_eu(4,4) -> 116 VGPR no-spill (R8/R9-verified).
// - Aggregation by fp32 atomicAdd at end of msg (R9-verified).
// - upd unchanged (R7-R9 verified).

typedef __attribute__((ext_vector_type(8))) short s16x8;   // MFMA A/B frag (8 bf16)
typedef __attribute__((ext_vector_type(4))) float f32x4;   // MFMA C/D frag

__device__ __forceinline__ unsigned short f2bf(float x) {
  union { float f; unsigned u; } v; v.f = x;
  unsigned r = v.u + 0x7fffu + ((v.u >> 16) & 1u);   // RNE
  return (unsigned short)(r >> 16);
}

__device__ __forceinline__ s16x8 ld_cvt8(const float* p) {
  float4 a = *(const float4*)p;
  float4 b = *(const float4*)(p + 4);
  union { s16x8 v; __hip_bfloat162 h2[4]; } u;
  float2 t;
  t.x = a.x; t.y = a.y; u.h2[0] = __float22bfloat162_rn(t);
  t.x = a.z; t.y = a.w; u.h2[1] = __float22bfloat162_rn(t);
  t.x = b.x; t.y = b.y; u.h2[2] = __float22bfloat162_rn(t);
  t.x = b.z; t.y = b.w; u.h2[3] = __float22bfloat162_rn(t);
  return u.v;
}

// ---------------- weight transpose+convert + agg zeroing ----------------
// ushort offsets in wts (global):
//  mW1t @0     : 128 rows x stride 168 (k<160, unswizzled; pad never read)
//  mW2t @21504 : 128 x 128, XOR-swizzled
//  mW3t @37888 :  64 x 128, XOR-swizzled
//  uW1t @46080 : 128 x 128, uW2t @62464, uW3t @78848 (64x128); total 87040 ushorts
__global__ __launch_bounds__(256) void wconv(
    const float* __restrict__ mW1, const float* __restrict__ mW2, const float* __restrict__ mW3,
    const float* __restrict__ uW1, const float* __restrict__ uW2, const float* __restrict__ uW3,
    unsigned short* __restrict__ wts, float* __restrict__ agg, int aggv4) {
  int t = blockIdx.x * 256 + threadIdx.x;
  if (t >= 86016) {
    int i = t - 86016;
    if (i < aggv4) ((float4*)agg)[i] = (float4){0.f, 0.f, 0.f, 0.f};
    return;
  }
  const float* src; int K, N, off, base;
  if      (t < 20480) { src = mW1; K = 160; N = 128; off = 0;     base = 0;     }
  else if (t < 36864) { src = mW2; K = 128; N = 128; off = 20480; base = 21504; }
  else if (t < 45056) { src = mW3; K = 128; N = 64;  off = 36864; base = 37888; }
  else if (t < 61440) { src = uW1; K = 128; N = 128; off = 45056; base = 46080; }
  else if (t < 77824) { src = uW2; K = 128; N = 128; off = 61440; base = 62464; }
  else                { src = uW3; K = 128; N = 64;  off = 77824; base = 78848; }
  int local = t - off;
  int n = local / K, k = local - n * K;
  int idx;
  if (K == 160) idx = n * 168 + k;                                        // mW1t: padded, plain
  else          idx = base + n * 128 + ((((k >> 3) ^ (n & 7)) << 3) | (k & 7));
  wts[idx] = f2bf(src[k * N + n]);
}

// bias LDS layout (floats, from bias base):
//  b1 @0   : [l15*12 + nt] nt<8  (stride 12 for b128 alignment + bank spread)
//  b2 @192 : same
//  b3 @384, g @448, bt @512 : [l15*4 + nt] nt<4
__device__ __forceinline__ void stage_bias(float* bf, int tid, int nthr,
    const float* b1, const float* b2, const float* b3,
    const float* g, const float* bt) {
  for (int i = tid; i < 576; i += nthr) {
    float v = 0.f;
    if (i < 192)      { int c = i;       int l = c / 12, nt = c % 12; if (nt < 8) v = b1[nt * 16 + l]; }
    else if (i < 384) { int c = i - 192; int l = c / 12, nt = c % 12; if (nt < 8) v = b2[nt * 16 + l]; }
    else if (i < 448) { int c = i - 384; int l = c / 4,  nt = c % 4;  v = b3[nt * 16 + l]; }
    else if (i < 512) { int c = i - 448; int l = c / 4,  nt = c % 4;  v = g[nt * 16 + l]; }
    else              { int c = i - 512; int l = c / 4,  nt = c % 4;  v = bt[nt * 16 + l]; }
    bf[i] = v;
  }
}

// ---------------- message MLP: 8 waves, 32 edges/tile/wave, dual-group + atomic agg ----------------
__global__ __attribute__((amdgpu_flat_work_group_size(512, 512), amdgpu_waves_per_eu(4, 4)))
void msg_kernel(
    const float* __restrict__ h, const int* __restrict__ ei, const float* __restrict__ ea,
    const unsigned short* __restrict__ wts,
    const float* __restrict__ mb1, const float* __restrict__ mb2, const float* __restrict__ mb3,
    const float* __restrict__ mg, const float* __restrict__ mbt,
    float* __restrict__ msg_out, float* __restrict__ agg, int E) {
  __shared__ __align__(16) unsigned short lds[80000];   // 160,000 B
  const int tid = threadIdx.x;
  const int w = tid >> 6, lane = tid & 63, quad = lane >> 4, l15 = lane & 15;
  const int sw = l15 & 7;
  const int* srcI = ei;
  const int* dstI = ei + E;
  const int ntiles = (E + 31) >> 5;
  const int stride = gridDim.x * 8;
  int tile = blockIdx.x * 8 + w;

  // ---- prefetch first tile's indices (rides under weight staging)
  int s1 = 0, d1 = 0, s2 = 0, d2 = 0;
  if (tile < ntiles) {
    int ep1 = (tile << 5) + l15, ep2 = (tile << 5) + 16 + l15;
    int ec1 = ep1 < E ? ep1 : E - 1;
    int ec2 = ep2 < E ? ep2 : E - 1;
    s1 = srcI[ec1]; d1 = dstI[ec1];
    s2 = srcI[ec2]; d2 = dstI[ec2];
  }

  // stage all msg weights (46080 ushorts) + biases once
  for (int i = tid; i < 5760; i += 512)
    *(s16x8*)&lds[i * 8] = *(const s16x8*)&wts[i * 8];
  float* bf = (float*)&lds[78848];
  stage_bias(bf, tid, 512, mb1, mb2, mb3, mg, mbt);
  __syncthreads();

  unsigned short* act = &lds[46080 + w * 4096];   // per-wave 8KB: 32 rows x 128, swizzled
  const unsigned short* W1 = &lds[0];
  const unsigned short* W2 = &lds[21504];
  const unsigned short* W3 = &lds[37888];

  for (; tile < ntiles; tile += stride) {
    const int e0 = tile << 5;
    int ec1 = (e0 + l15) < E ? (e0 + l15) : E - 1;
    int ec2 = (e0 + 16 + l15) < E ? (e0 + 16 + l15) : E - 1;
    // ---- gather both 16-edge groups' A-fragments (indices already in regs)
    const float* rs1 = h + (size_t)s1 * 64 + quad * 8;
    const float* rd1 = h + (size_t)d1 * 64 + quad * 8;
    const float* re1 = ea + (size_t)ec1 * 32 + quad * 8;
    const float* rs2 = h + (size_t)s2 * 64 + quad * 8;
    const float* rd2 = h + (size_t)d2 * 64 + quad * 8;
    const float* re2 = ea + (size_t)ec2 * 32 + quad * 8;
    s16x8 fa1[5], fa2[5];
    fa1[0] = ld_cvt8(rs1); fa1[1] = ld_cvt8(rs1 + 32);
    fa1[2] = ld_cvt8(rd1); fa1[3] = ld_cvt8(rd1 + 32);
    fa1[4] = ld_cvt8(re1);
    fa2[0] = ld_cvt8(rs2); fa2[1] = ld_cvt8(rs2 + 32);
    fa2[2] = ld_cvt8(rd2); fa2[3] = ld_cvt8(rd2 + 32);
    fa2[4] = ld_cvt8(re2);

    // ---- prefetch next tile's indices (s1/s2 regs dead after gather issue;
    //      d1/d2 still live for the atomic phase -> separate next-regs)
    int s1n = 0, d1n = 0, s2n = 0, d2n = 0;
    {
      int tn = tile + stride;
      if (tn < ntiles) {
        int en1 = (tn << 5) + l15, en2 = (tn << 5) + 16 + l15;
        int en1c = en1 < E ? en1 : E - 1;
        int en2c = en2 < E ? en2 : E - 1;
        s1n = srcI[en1c]; d1n = dstI[en1c];
        s2n = srcI[en2c]; d2n = dstI[en2c];
      }
    }

    // ---- L1: 160 -> 128; each W1 fragment feeds both groups
    f32x4 aA[8], aB[8];
    #pragma unroll
    for (int nt = 0; nt < 8; nt++) { aA[nt] = (f32x4){0.f,0.f,0.f,0.f}; aB[nt] = (f32x4){0.f,0.f,0.f,0.f}; }
    #pragma unroll
    for (int kb = 0; kb < 5; kb++) {
      #pragma unroll
      for (int nt = 0; nt < 8; nt++) {
        s16x8 b = *(const s16x8*)&W1[(nt * 16 + l15) * 168 + kb * 32 + quad * 8];
        aA[nt] = __builtin_amdgcn_mfma_f32_16x16x32_bf16(fa1[kb], b, aA[nt], 0, 0, 0);
        aB[nt] = __builtin_amdgcn_mfma_f32_16x16x32_bf16(fa2[kb], b, aB[nt], 0, 0, 0);
      }
    }
    // act1 = relu(acc + b1); rows 0-15 = group1, 16-31 = group2
    {
      union { float4 v[2]; float f[8]; } b1u;
      b1u.v[0] = *(const float4*)&bf[l15 * 12];
      b1u.v[1] = *(const float4*)&bf[l15 * 12 + 4];
      #pragma unroll
      for (int g = 0; g < 2; g++) {
        #pragma unroll
        for (int nt = 0; nt < 8; nt++) {
          int cb = 2 * nt + (l15 >> 3);
          #pragma unroll
          for (int r = 0; r < 4; r++) {
            int row = g * 16 + quad * 4 + r;
            int cbx = cb ^ (row & 7) ^ ((row >> 3) << 2);
            float v = (g ? aB[nt][r] : aA[nt][r]) + b1u.f[nt];
            v = v > 0.f ? v : 0.f;
            act[row * 128 + (cbx << 3) + sw] = f2bf(v);
          }
        }
      }
    }

    // ---- L2: 128 -> 128; A-frags for both groups, B shared
    f32x4 cA[8], cB[8];
    #pragma unroll
    for (int nt = 0; nt < 8; nt++) { cA[nt] = (f32x4){0.f,0.f,0.f,0.f}; cB[nt] = (f32x4){0.f,0.f,0.f,0.f}; }
    const int hi1 = (l15 >> 3) << 2;        // (row>>3)<<2 for row=l15
    const int hi2 = (2 + (l15 >> 3)) << 2;  // for row=16+l15
    #pragma unroll
    for (int kb = 0; kb < 4; kb++) {
      int base = (kb << 2) + quad;
      s16x8 a1 = *(const s16x8*)&act[l15 * 128 + (((base ^ sw ^ hi1)) << 3)];
      s16x8 a2 = *(const s16x8*)&act[(16 + l15) * 128 + (((base ^ sw ^ hi2)) << 3)];
      int wblk = (base ^ sw) << 3;
      #pragma unroll
      for (int nt = 0; nt < 8; nt++) {
        s16x8 b = *(const s16x8*)&W2[(nt * 16 + l15) * 128 + wblk];
        cA[nt] = __builtin_amdgcn_mfma_f32_16x16x32_bf16(a1, b, cA[nt], 0, 0, 0);
        cB[nt] = __builtin_amdgcn_mfma_f32_16x16x32_bf16(a2, b, cB[nt], 0, 0, 0);
      }
    }
    {
      union { float4 v[2]; float f[8]; } b2u;
      b2u.v[0] = *(const float4*)&bf[192 + l15 * 12];
      b2u.v[1] = *(const float4*)&bf[192 + l15 * 12 + 4];
      #pragma unroll
      for (int g = 0; g < 2; g++) {
        #pragma unroll
        for (int nt = 0; nt < 8; nt++) {
          int cb = 2 * nt + (l15 >> 3);
          #pragma unroll
          for (int r = 0; r < 4; r++) {
            int row = g * 16 + quad * 4 + r;
            int cbx = cb ^ (row & 7) ^ ((row >> 3) << 2);
            float v = (g ? cB[nt][r] : cA[nt][r]) + b2u.f[nt];
            v = v > 0.f ? v : 0.f;
            act[row * 128 + (cbx << 3) + sw] = f2bf(v);
          }
        }
      }
    }

    // ---- L3: 128 -> 64
    f32x4 dA[4], dB[4];
    #pragma unroll
    for (int nt = 0; nt < 4; nt++) { dA[nt] = (f32x4){0.f,0.f,0.f,0.f}; dB[nt] = (f32x4){0.f,0.f,0.f,0.f}; }
    #pragma unroll
    for (int kb = 0; kb < 4; kb++) {
      int base = (kb << 2) + quad;
      s16x8 a1 = *(const s16x8*)&act[l15 * 128 + (((base ^ sw ^ hi1)) << 3)];
      s16x8 a2 = *(const s16x8*)&act[(16 + l15) * 128 + (((base ^ sw ^ hi2)) << 3)];
      int wblk = (base ^ sw) << 3;
      #pragma unroll
      for (int nt = 0; nt < 4; nt++) {
        s16x8 b = *(const s16x8*)&W3[(nt * 16 + l15) * 128 + wblk];
        dA[nt] = __builtin_amdgcn_mfma_f32_16x16x32_bf16(a1, b, dA[nt], 0, 0, 0);
        dB[nt] = __builtin_amdgcn_mfma_f32_16x16x32_bf16(a2, b, dB[nt], 0, 0, 0);
      }
    }

    // ---- LayerNorm in registers + store msg + atomic aggregate into agg[dst]
    {
      union { float4 v; float f[4]; } b3u, gu, btu;
      b3u.v = *(const float4*)&bf[384 + l15 * 4];
      gu.v  = *(const float4*)&bf[448 + l15 * 4];
      btu.v = *(const float4*)&bf[512 + l15 * 4];
      #pragma unroll
      for (int g = 0; g < 2; g++) {
        #pragma unroll
        for (int r = 0; r < 4; r++) {
          float v0 = (g ? dB[0][r] : dA[0][r]) + b3u.f[0];
          float v1 = (g ? dB[1][r] : dA[1][r]) + b3u.f[1];
          float v2 = (g ? dB[2][r] : dA[2][r]) + b3u.f[2];
          float v3 = (g ? dB[3][r] : dA[3][r]) + b3u.f[3];
          float p = v0 + v1 + v2 + v3;
          float q = v0 * v0 + v1 * v1 + v2 * v2 + v3 * v3;
          #pragma unroll
          for (int m = 1; m <= 8; m <<= 1) {
            p += __shfl_xor(p, m);
            q += __shfl_xor(q, m);
          }
          float mu = p * (1.f / 64.f);
          float var = q * (1.f / 64.f) - mu * mu;
          float rstd = rsqrtf(var + 1e-5f);
          int row = e0 + g * 16 + quad * 4 + r;
          if (row < E) {
            float o0 = (v0 - mu) * rstd * gu.f[0] + btu.f[0];
            float o1 = (v1 - mu) * rstd * gu.f[1] + btu.f[1];
            float o2 = (v2 - mu) * rstd * gu.f[2] + btu.f[2];
            float o3 = (v3 - mu) * rstd * gu.f[3] + btu.f[3];
            float* mp = msg_out + (size_t)row * 64 + l15;
            mp[0]  = o0;
            mp[16] = o1;
            mp[32] = o2;
            mp[48] = o3;
            // dst of this row's edge lives in lane (quad*4+r) of the same group
            int dd = __shfl(g ? d2 : d1, quad * 4 + r);
            float* ap = agg + (size_t)dd * 64 + l15;
            atomicAdd(ap,      o0);
            atomicAdd(ap + 16, o1);
            atomicAdd(ap + 32, o2);
            atomicAdd(ap + 48, o3);
          }
        }
      }
    }

    // rotate prefetched indices into current
    s1 = s1n; d1 = d1n; s2 = s2n; d2 = d2n;
  }
}

// ---------------- update MLP: 16 waves, 16 nodes/tile/wave (R7-R9 verified) ----------------
__global__ __attribute__((amdgpu_flat_work_group_size(1024, 1024), amdgpu_waves_per_eu(4, 4)))
void upd_kernel(
    const float* __restrict__ h, const float* __restrict__ agg,
    const unsigned short* __restrict__ wts,
    const float* __restrict__ ub1, const float* __restrict__ ub2, const float* __restrict__ ub3,
    const float* __restrict__ ug, const float* __restrict__ ubt,
    float* __restrict__ h_new, int Nn) {
  __shared__ __align__(16) unsigned short lds[74880];   // 149,760 B
  const int tid = threadIdx.x;
  const int w = tid >> 6, lane = tid & 63, quad = lane >> 4, l15 = lane & 15;
  const int sw = l15 & 7;
  const int ntiles = (Nn + 15) >> 4;
  const int stride = gridDim.x * 16;
  int tile = blockIdx.x * 16 + w;

  float4 P[8];
  if (tile < ntiles) {
    int n = (tile << 4) + l15; int nc = n < Nn ? n : 0;
    const float* rh = h + (size_t)nc * 64 + quad * 8;
    const float* rg = agg + (size_t)nc * 64 + quad * 8;
    P[0] = *(const float4*)rh;        P[1] = *(const float4*)(rh + 4);
    P[2] = *(const float4*)(rh + 32); P[3] = *(const float4*)(rh + 36);
    P[4] = *(const float4*)rg;        P[5] = *(const float4*)(rg + 4);
    P[6] = *(const float4*)(rg + 32); P[7] = *(const float4*)(rg + 36);
  }

  for (int i = tid; i < 5120; i += 1024)
    *(s16x8*)&lds[i * 8] = *(const s16x8*)&wts[46080 + i * 8];
  float* bf = (float*)&lds[73728];
  stage_bias(bf, tid, 1024, ub1, ub2, ub3, ug, ubt);
  __syncthreads();

  unsigned short* act = &lds[40960 + w * 2048];
  const unsigned short* W1 = &lds[0];
  const unsigned short* W2 = &lds[16384];
  const unsigned short* W3 = &lds[32768];

  for (; tile < ntiles; tile += stride) {
    const int n0 = tile << 4;
    s16x8 fa[4];
    {
      union { s16x8 v; __hip_bfloat162 h2[4]; } u0, u1, u2, u3;
      float2 t;
      t.x = P[0].x; t.y = P[0].y; u0.h2[0] = __float22bfloat162_rn(t);
      t.x = P[0].z; t.y = P[0].w; u0.h2[1] = __float22bfloat162_rn(t);
      t.x = P[1].x; t.y = P[1].y; u0.h2[2] = __float22bfloat162_rn(t);
      t.x = P[1].z; t.y = P[1].w; u0.h2[3] = __float22bfloat162_rn(t);
      t.x = P[2].x; t.y = P[2].y; u1.h2[0] = __float22bfloat162_rn(t);
      t.x = P[2].z; t.y = P[2].w; u1.h2[1] = __float22bfloat162_rn(t);
      t.x = P[3].x; t.y = P[3].y; u1.h2[2] = __float22bfloat162_rn(t);
      t.x = P[3].z; t.y = P[3].w; u1.h2[3] = __float22bfloat162_rn(t);
      t.x = P[4].x; t.y = P[4].y; u2.h2[0] = __float22bfloat162_rn(t);
      t.x = P[4].z; t.y = P[4].w; u2.h2[1] = __float22bfloat162_rn(t);
      t.x = P[5].x; t.y = P[5].y; u2.h2[2] = __float22bfloat162_rn(t);
      t.x = P[5].z; t.y = P[5].w; u2.h2[3] = __float22bfloat162_rn(t);
      t.x = P[6].x; t.y = P[6].y; u3.h2[0] = __float22bfloat162_rn(t);
      t.x = P[6].z; t.y = P[6].w; u3.h2[1] = __float22bfloat162_rn(t);
      t.x = P[7].x; t.y = P[7].y; u3.h2[2] = __float22bfloat162_rn(t);
      t.x = P[7].z; t.y = P[7].w; u3.h2[3] = __float22bfloat162_rn(t);
      fa[0] = u0.v; fa[1] = u1.v; fa[2] = u2.v; fa[3] = u3.v;
    }

    {
      int tn = tile + stride;
      if (tn < ntiles) {
        int n = (tn << 4) + l15; int nc = n < Nn ? n : 0;
        const float* rh = h + (size_t)nc * 64 + quad * 8;
        const float* rg = agg + (size_t)nc * 64 + quad * 8;
        P[0] = *(const float4*)rh;        P[1] = *(const float4*)(rh + 4);
        P[2] = *(const float4*)(rh + 32); P[3] = *(const float4*)(rh + 36);
        P[4] = *(const float4*)rg;        P[5] = *(const float4*)(rg + 4);
        P[6] = *(const float4*)(rg + 32); P[7] = *(const float4*)(rg + 36);
      }
    }

    f32x4 acc[8];
    #pragma unroll
    for (int nt = 0; nt < 8; nt++) acc[nt] = (f32x4){0.f, 0.f, 0.f, 0.f};
    #pragma unroll
    for (int kb = 0; kb < 4; kb++) {
      int blk8 = (((kb << 2) + quad) ^ sw) << 3;
      #pragma unroll
      for (int nt = 0; nt < 8; nt++) {
        s16x8 b = *(const s16x8*)&W1[(nt * 16 + l15) * 128 + blk8];
        acc[nt] = __builtin_amdgcn_mfma_f32_16x16x32_bf16(fa[kb], b, acc[nt], 0, 0, 0);
      }
    }
    {
      union { float4 v[2]; float f[8]; } b1u;
      b1u.v[0] = *(const float4*)&bf[l15 * 12];
      b1u.v[1] = *(const float4*)&bf[l15 * 12 + 4];
      #pragma unroll
      for (int nt = 0; nt < 8; nt++) {
        int cb = 2 * nt + (l15 >> 3);
        #pragma unroll
        for (int r = 0; r < 4; r++) {
          int row = quad * 4 + r;
          float v = acc[nt][r] + b1u.f[nt];
          v = v > 0.f ? v : 0.f;
          act[row * 128 + ((cb ^ (row & 7)) << 3) + sw] = f2bf(v);
        }
      }
    }

    f32x4 acc2[8];
    #pragma unroll
    for (int nt = 0; nt < 8; nt++) acc2[nt] = (f32x4){0.f, 0.f, 0.f, 0.f};
    #pragma unroll
    for (int kb = 0; kb < 4; kb++) {
      int blk8 = (((kb << 2) + quad) ^ sw) << 3;
      s16x8 a = *(const s16x8*)&act[l15 * 128 + blk8];
      #pragma unroll
      for (int nt = 0; nt < 8; nt++) {
        s16x8 b = *(const s16x8*)&W2[(nt * 16 + l15) * 128 + blk8];
        acc2[nt] = __builtin_amdgcn_mfma_f32_16x16x32_bf16(a, b, acc2[nt], 0, 0, 0);
      }
    }
    {
      union { float4 v[2]; float f[8]; } b2u;
      b2u.v[0] = *(const float4*)&bf[192 + l15 * 12];
      b2u.v[1] = *(const float4*)&bf[192 + l15 * 12 + 4];
      #pragma unroll
      for (int nt = 0; nt < 8; nt++) {
        int cb = 2 * nt + (l15 >> 3);
        #pragma unroll
        for (int r = 0; r < 4; r++) {
          int row = quad * 4 + r;
          float v = acc2[nt][r] + b2u.f[nt];
          v = v > 0.f ? v : 0.f;
          act[row * 128 + ((cb ^ (row & 7)) << 3) + sw] = f2bf(v);
        }
      }
    }

    f32x4 acc3[4];
    #pragma unroll
    for (int nt = 0; nt < 4; nt++) acc3[nt] = (f32x4){0.f, 0.f, 0.f, 0.f};
    #pragma unroll
    for (int kb = 0; kb < 4; kb++) {
      int blk8 = (((kb << 2) + quad) ^ sw) << 3;
      s16x8 a = *(const s16x8*)&act[l15 * 128 + blk8];
      #pragma unroll
      for (int nt = 0; nt < 4; nt++) {
        s16x8 b = *(const s16x8*)&W3[(nt * 16 + l15) * 128 + blk8];
        acc3[nt] = __builtin_amdgcn_mfma_f32_16x16x32_bf16(a, b, acc3[nt], 0, 0, 0);
      }
    }

    {
      union { float4 v; float f[4]; } b3u, gu, btu;
      b3u.v = *(const float4*)&bf[384 + l15 * 4];
      gu.v  = *(const float4*)&bf[448 + l15 * 4];
      btu.v = *(const float4*)&bf[512 + l15 * 4];
      #pragma unroll
      for (int r = 0; r < 4; r++) {
        float v0 = acc3[0][r] + b3u.f[0];
        float v1 = acc3[1][r] + b3u.f[1];
        float v2 = acc3[2][r] + b3u.f[2];
        float v3 = acc3[3][r] + b3u.f[3];
        float p = v0 + v1 + v2 + v3;
        float q = v0 * v0 + v1 * v1 + v2 * v2 + v3 * v3;
        #pragma unroll
        for (int m = 1; m <= 8; m <<= 1) {
          p += __shfl_xor(p, m);
          q += __shfl_xor(q, m);
        }
        float mu = p * (1.f / 64.f);
        float var = q * (1.f / 64.f) - mu * mu;
        float rstd = rsqrtf(var + 1e-5f);
        int row = n0 + quad * 4 + r;
        if (row < Nn) {
          const float* hp = h + (size_t)row * 64 + l15;
          float* op = h_new + (size_t)row * 64 + l15;
          op[0]  = (v0 - mu) * rstd * gu.f[0] + btu.f[0] + hp[0];
          op[16] = (v1 - mu) * rstd * gu.f[1] + btu.f[1] + hp[16];
          op[32] = (v2 - mu) * rstd * gu.f[2] + btu.f[2] + hp[32];
          op[48] = (v3 - mu) * rstd * gu.f[3] + btu.f[3] + hp[48];
        }
      }
    }
  }
}

extern "C" void kernel_launch(void* const* d_in, const int* in_sizes, int n_in,
                              void* d_out, int out_size, void* d_ws, size_t ws_size,
                              hipStream_t stream) {
  const float* h   = (const float*)d_in[0];
  const int*   ei  = (const int*)d_in[1];
  const float* ea  = (const float*)d_in[2];
  const float* mW1 = (const float*)d_in[3];
  const float* mb1 = (const float*)d_in[4];
  const float* mW2 = (const float*)d_in[5];
  const float* mb2 = (const float*)d_in[6];
  const float* mW3 = (const float*)d_in[7];
  const float* mb3 = (const float*)d_in[8];
  const float* mg  = (const float*)d_in[9];
  const float* mbt = (const float*)d_in[10];
  const float* uW1 = (const float*)d_in[11];
  const float* ub1 = (const float*)d_in[12];
  const float* uW2 = (const float*)d_in[13];
  const float* ub2 = (const float*)d_in[14];
  const float* uW3 = (const float*)d_in[15];
  const float* ub3 = (const float*)d_in[16];
  const float* ug  = (const float*)d_in[17];
  const float* ubt = (const float*)d_in[18];

  const int N = in_sizes[0] / 64;
  const int E = in_sizes[2] / 32;

  char* ws = (char*)d_ws;
  float* agg          = (float*)ws;              ws += (size_t)N * 64 * 4;
  unsigned short* wts = (unsigned short*)ws;     ws += 87040 * 2;

  float* h_new = (float*)d_out;
  float* msg   = (float*)d_out + (size_t)N * 64;

  const int aggv4 = N * 16;                       // N*64 floats / 4
  const int wz_threads = 86016 + aggv4;
  wconv<<<dim3((wz_threads + 255) / 256), dim3(256), 0, stream>>>(
      mW1, mW2, mW3, uW1, uW2, uW3, wts, agg, aggv4);
  msg_kernel<<<dim3(256), dim3(512), 0, stream>>>(
      h, ei, ea, wts, mb1, mb2, mb3, mg, mbt, msg, agg, E);
  upd_kernel<<<dim3(256), dim3(1024), 0, stream>>>(
      h, agg, wts, ub1, ub2, ub3, ug, ubt, h_new, N);
}